// Round 5
// baseline (437.095 us; speedup 1.0000x reference)
//
#include <hip/hip_runtime.h>
#include <math.h>

#define N_NODES 200000
#define NGRAPH  512
#define HID     256

typedef __attribute__((ext_vector_type(8))) short s16x8;
typedef __attribute__((ext_vector_type(4))) float f32x4;

__device__ __forceinline__ unsigned short f2bf_rne(float f) {
  unsigned int u = __float_as_uint(f);
  return (unsigned short)((u + 0x7fffu + ((u >> 16) & 1u)) >> 16);
}
__device__ __forceinline__ unsigned int pack2_bf16_rne(float a, float b) {
  unsigned int ua = __float_as_uint(a), ub = __float_as_uint(b);
  unsigned int ra = (ua + 0x7fffu + ((ua >> 16) & 1u)) >> 16;
  unsigned int rb = (ub + 0x7fffu + ((ub >> 16) & 1u)) & 0xffff0000u;
  return ra | rb;
}

// ---------------------------------------------------------------------------
// Kernel 1: per-part fused gate+pool partials. Block = (segment, half).
// No barriers in the hot loop; all loads direct global -> registers.
// Writes partial record [sum(256) | max(256) | attn(256) | m | den | cnt].
// ---------------------------------------------------------------------------
__global__ __launch_bounds__(256, 3) void pool_partial(
    const float* __restrict__ x, const int* __restrict__ batch,
    const float* __restrict__ w1, const float* __restrict__ b1,
    const float* __restrict__ w2, const float* __restrict__ b2,
    float* __restrict__ pbuf)
{
  __shared__ __align__(16) short w1T[64 * 264];  // bf16 w1^T [n][k], pitch 264 (2-way-free)
  __shared__ int sb[2];
  __shared__ float sm[4], sd[4];

  const int tid = threadIdx.x;
  const int w = tid >> 6, lane = tid & 63, q = lane >> 4, c = lane & 15;
  const int seg = blockIdx.x >> 1, p = blockIdx.x & 1;

  if (tid < 2) {  // lower_bound(batch, seg) / lower_bound(batch, seg+1)
    int target = seg + tid;
    int lo = 0, hi = N_NODES;
    while (lo < hi) { int mid = (lo + hi) >> 1; if (batch[mid] < target) lo = mid + 1; else hi = mid; }
    sb[tid] = lo;
  }
  for (int i = tid; i < 256 * 64; i += 256) {  // i = k*64 + n, coalesced
    int k = i >> 6, n = i & 63;
    w1T[n * 264 + k] = (short)f2bf_rne(w1[i]);
  }
  __syncthreads();

  const int s0 = sb[0], e0 = sb[1];
  const int len = e0 - s0;
  const int ps = s0 + ((len * p) >> 1);
  const int pe = s0 + ((len * (p + 1)) >> 1);
  const int plen = pe - ps;

  float b1v[4], w2v[4];
#pragma unroll
  for (int nt = 0; nt < 4; ++nt) { b1v[nt] = b1[nt * 16 + c]; w2v[nt] = w2[nt * 16 + c]; }
  const float b2v = b2[0];

  f32x4 sum = (f32x4){0.f, 0.f, 0.f, 0.f};
  f32x4 mx  = (f32x4){-INFINITY, -INFINITY, -INFINITY, -INFINITY};
  f32x4 at  = (f32x4){0.f, 0.f, 0.f, 0.f};
  float den = 0.f, m = -INFINITY;

  const int ntiles = (plen + 15) >> 4;
  for (int t = w; t < ntiles; t += 4) {
    const int r0 = ps + (t << 4);
    const int lim = min(16, pe - r0);   // wave-uniform

    // A-fragment loads: row = r0 + c (clamped), k = kt*32 + q*8 + j
    const int rowA = r0 + (c < lim ? c : 0);
    const float* ap = x + (size_t)rowA * HID + q * 8;
    float4 fa0[8], fa1[8];
#pragma unroll
    for (int kt = 0; kt < 8; ++kt) {
      fa0[kt] = *(const float4*)(ap + kt * 32);
      fa1[kt] = *(const float4*)(ap + kt * 32 + 4);
    }
    union { s16x8 v; unsigned int u[4]; } ah[8];
#pragma unroll
    for (int kt = 0; kt < 8; ++kt) {
      ah[kt].u[0] = pack2_bf16_rne(fa0[kt].x, fa0[kt].y);
      ah[kt].u[1] = pack2_bf16_rne(fa0[kt].z, fa0[kt].w);
      ah[kt].u[2] = pack2_bf16_rne(fa1[kt].x, fa1[kt].y);
      ah[kt].u[3] = pack2_bf16_rne(fa1[kt].z, fa1[kt].w);
    }

    // pool-layout loads issued now so their (cache-hot) latency hides under MFMA
    float4 pv[16];
#pragma unroll
    for (int i = 0; i < 16; ++i) {
      int rr = r0 + (i < lim ? i : 0);
      pv[i] = *(const float4*)(x + (size_t)rr * HID + lane * 4);
    }

    f32x4 acc[4];
#pragma unroll
    for (int nt = 0; nt < 4; ++nt) acc[nt] = (f32x4){0.f, 0.f, 0.f, 0.f};
#pragma unroll
    for (int kt = 0; kt < 8; ++kt) {
#pragma unroll
      for (int nt = 0; nt < 4; ++nt) {
        s16x8 bh = *(const s16x8*)&w1T[(nt * 16 + c) * 264 + kt * 32 + q * 8];
        acc[nt] = __builtin_amdgcn_mfma_f32_16x16x32_bf16(ah[kt].v, bh, acc[nt], 0, 0, 0);
      }
    }

    // epilogue: D[row=4q+r][col=nt*16+c]; butterfly over c -> gr[r] = g(row 4q+r)
    float gr[4];
#pragma unroll
    for (int r = 0; r < 4; ++r) {
      float sv = 0.f;
#pragma unroll
      for (int nt = 0; nt < 4; ++nt) {
        float h = acc[nt][r] + b1v[nt];
        h = h > 0.f ? h : 0.f;
        sv += h * w2v[nt];
      }
      sv += __shfl_xor(sv, 1, 64);
      sv += __shfl_xor(sv, 2, 64);
      sv += __shfl_xor(sv, 4, 64);
      sv += __shfl_xor(sv, 8, 64);
      gr[r] = sv + b2v;
    }

    // gather all 16 row-gates once; tile max over valid rows
    float gv16[16];
    float gm = -INFINITY;
#pragma unroll
    for (int i = 0; i < 16; ++i) {
      gv16[i] = __shfl(gr[i & 3], (i >> 2) << 4, 64);
      if (i < lim) gm = fmaxf(gm, gv16[i]);
    }
    float m_new = fmaxf(m, gm);
    float alpha = (m == -INFINITY) ? 0.f : __expf(m - m_new);
    at = at * alpha;
    den *= alpha;
    m = m_new;

#pragma unroll
    for (int i = 0; i < 16; ++i) {
      if (i < lim) {   // wave-uniform branch
        float ei = __expf(gv16[i] - m_new);
        den += ei;
        f32x4 f = (f32x4){pv[i].x, pv[i].y, pv[i].z, pv[i].w};
        sum = sum + f;
        mx[0] = fmaxf(mx[0], f[0]); mx[1] = fmaxf(mx[1], f[1]);
        mx[2] = fmaxf(mx[2], f[2]); mx[3] = fmaxf(mx[3], f[3]);
        at[0] = fmaf(ei, f[0], at[0]); at[1] = fmaf(ei, f[1], at[1]);
        at[2] = fmaf(ei, f[2], at[2]); at[3] = fmaf(ei, f[3], at[3]);
      }
    }
  }

  __syncthreads();                 // everyone done with w1T; reuse as merge scratch
  float* scr = (float*)w1T;        // needs 3072 floats = 12 KB <= 33 KB
  {
    float* p0 = scr + (w * 3 + 0) * 256;
    float* p1 = scr + (w * 3 + 1) * 256;
    float* p2 = scr + (w * 3 + 2) * 256;
    int f = lane * 4;
#pragma unroll
    for (int j = 0; j < 4; ++j) { p0[f + j] = sum[j]; p1[f + j] = mx[j]; p2[f + j] = at[j]; }
    if (lane == 0) { sm[w] = m; sd[w] = den; }
  }
  __syncthreads();
  {
    int f = tid;
    float M = fmaxf(fmaxf(sm[0], sm[1]), fmaxf(sm[2], sm[3]));
    float S = 0.f, MX = -INFINITY, A = 0.f, D = 0.f;
#pragma unroll
    for (int ww = 0; ww < 4; ++ww) {
      float sc = (sm[ww] == -INFINITY) ? 0.f : __expf(sm[ww] - M);
      S += scr[(ww * 3 + 0) * 256 + f];
      MX = fmaxf(MX, scr[(ww * 3 + 1) * 256 + f]);
      A = fmaf(sc, scr[(ww * 3 + 2) * 256 + f], A);
      D = fmaf(sc, sd[ww], D);
    }
    float* pr = pbuf + (size_t)blockIdx.x * 772;
    pr[f] = S; pr[256 + f] = MX; pr[512 + f] = A;
    if (tid == 0) { pr[768] = M; pr[769] = D; pr[770] = (float)plen; }
  }
}

// ---------------------------------------------------------------------------
// Kernel 2: merge the 2 partials per segment -> z (512 x 768 fp32).
// ---------------------------------------------------------------------------
__global__ __launch_bounds__(256) void pool_merge(
    const float* __restrict__ pbuf, float* __restrict__ zbuf)
{
  const int seg = blockIdx.x;
  const int f = threadIdx.x;
  const float* pa = pbuf + (size_t)(seg * 2) * 772;
  const float* pb = pa + 772;
  float m0 = pa[768], d0 = pa[769], c0 = pa[770];
  float m1 = pb[768], d1 = pb[769], c1 = pb[770];
  float M = fmaxf(m0, m1);
  float sc0 = (m0 == -INFINITY) ? 0.f : __expf(m0 - M);
  float sc1 = (m1 == -INFINITY) ? 0.f : __expf(m1 - M);
  float D = sc0 * d0 + sc1 * d1;
  float cnt = c0 + c1;
  float S  = pa[f] + pb[f];
  float MX = fmaxf(pa[256 + f], pb[256 + f]);
  float A  = sc0 * pa[512 + f] + sc1 * pb[512 + f];
  float* zr = zbuf + (size_t)seg * 768;
  zr[f]       = (cnt > 0.f) ? S / cnt : 0.f;
  zr[256 + f] = (cnt > 0.f) ? MX : 0.f;
  zr[512 + f] = (cnt > 0.f) ? A / fmaxf(D, 1e-16f) : 0.f;
}

// ---------------------------------------------------------------------------
// Kernel 3: y = z @ wp + bp, LayerNorm, fp32 out. Block = 1 graph; k-dim
// split across 4 waves; wp loaded as float4 (1 KB/wave-instr, coalesced).
// ---------------------------------------------------------------------------
__global__ __launch_bounds__(256) void head_ln(
    const float* __restrict__ zbuf, const float* __restrict__ wp,
    const float* __restrict__ bp, const float* __restrict__ gam,
    const float* __restrict__ bet, float* __restrict__ out)
{
  const int g = blockIdx.x;
  const int tid = threadIdx.x;
  const int w = tid >> 6, lane = tid & 63;
  __shared__ float z[768];
  __shared__ __align__(16) float part[4][256];
  __shared__ float red[256];

  for (int i = tid; i < 768; i += 256) z[i] = zbuf[(size_t)g * 768 + i];
  __syncthreads();

  // wave w: k in [w*192, (w+1)*192); lane owns cols lane*4 .. lane*4+3
  f32x4 acc = (f32x4){0.f, 0.f, 0.f, 0.f};
  const float4* wp4 = (const float4*)wp;  // wp[k*256 + lane*4] = wp4[k*64 + lane]
  const int k0 = w * 192;
#pragma unroll 8
  for (int k = k0; k < k0 + 192; ++k) {
    float4 wv = wp4[(size_t)k * 64 + lane];
    float zk = z[k];
    acc[0] = fmaf(zk, wv.x, acc[0]);
    acc[1] = fmaf(zk, wv.y, acc[1]);
    acc[2] = fmaf(zk, wv.z, acc[2]);
    acc[3] = fmaf(zk, wv.w, acc[3]);
  }
  *(f32x4*)&part[w][lane * 4] = acc;
  __syncthreads();

  const int t = tid;
  float y = bp[t] + part[0][t] + part[1][t] + part[2][t] + part[3][t];

  red[t] = y;
  __syncthreads();
  for (int wd = 128; wd > 0; wd >>= 1) {
    if (t < wd) red[t] += red[t + wd];
    __syncthreads();
  }
  const float mu = red[0] * (1.f / 256.f);
  __syncthreads();
  float d = y - mu;
  red[t] = d * d;
  __syncthreads();
  for (int wd = 128; wd > 0; wd >>= 1) {
    if (t < wd) red[t] += red[t + wd];
    __syncthreads();
  }
  const float var = red[0] * (1.f / 256.f);
  const float is = rsqrtf(var + 1e-5f);
  out[(size_t)g * 256 + t] = fmaf(d * is, gam[t], bet[t]);
}

// ---------------------------------------------------------------------------
extern "C" void kernel_launch(void* const* d_in, const int* in_sizes, int n_in,
                              void* d_out, int out_size, void* d_ws, size_t ws_size,
                              hipStream_t stream) {
  const float* x   = (const float*)d_in[0];
  const int*   bat = (const int*)d_in[1];
  const float* w1  = (const float*)d_in[2];
  const float* b1  = (const float*)d_in[3];
  const float* w2  = (const float*)d_in[4];
  const float* b2  = (const float*)d_in[5];
  const float* wp  = (const float*)d_in[6];
  const float* bp  = (const float*)d_in[7];
  const float* gam = (const float*)d_in[8];
  const float* bet = (const float*)d_in[9];
  float* out = (float*)d_out;

  // ws layout: pbuf 1024*772 f32 (3,162,112 B) @ 0; zbuf 512*768 f32 after.
  float* pbuf = (float*)d_ws;
  float* zbuf = (float*)((char*)d_ws + (size_t)1024 * 772 * 4);

  hipLaunchKernelGGL(pool_partial, dim3(NGRAPH * 2), dim3(256), 0, stream,
                     x, bat, w1, b1, w2, b2, pbuf);
  hipLaunchKernelGGL(pool_merge, dim3(NGRAPH), dim3(256), 0, stream, pbuf, zbuf);
  hipLaunchKernelGGL(head_ln, dim3(NGRAPH), dim3(256), 0, stream,
                     zbuf, wp, bp, gam, bet, out);
}

// Round 6
// 398.438 us; speedup vs baseline: 1.0970x; 1.0970x over previous
//
#include <hip/hip_runtime.h>
#include <math.h>

#define N_NODES 200000
#define NGRAPH  512
#define HID     256

typedef __attribute__((ext_vector_type(8))) short s16x8;
typedef __attribute__((ext_vector_type(4))) float f32x4;

__device__ __forceinline__ unsigned short f2bf_rne(float f) {
  unsigned int u = __float_as_uint(f);
  return (unsigned short)((u + 0x7fffu + ((u >> 16) & 1u)) >> 16);
}
__device__ __forceinline__ unsigned int pack2_bf16_rne(float a, float b) {
  unsigned int ua = __float_as_uint(a), ub = __float_as_uint(b);
  unsigned int ra = (ua + 0x7fffu + ((ua >> 16) & 1u)) >> 16;
  unsigned int rb = (ub + 0x7fffu + ((ub >> 16) & 1u)) & 0xffff0000u;
  return ra | rb;
}

// ---------------------------------------------------------------------------
// Kernel 1: per-part fused gate+pool partials. Block = (segment, half).
// No barriers in the hot loop. Pool rows loaded per-iteration (L1/L2 hot from
// the A-fragment loads) — NOT prefetched into a register array (R5 spilled).
// ---------------------------------------------------------------------------
__global__ __launch_bounds__(256, 4) void pool_partial(
    const float* __restrict__ x, const int* __restrict__ batch,
    const float* __restrict__ w1, const float* __restrict__ b1,
    const float* __restrict__ w2, const float* __restrict__ b2,
    float* __restrict__ pbuf)
{
  __shared__ __align__(16) short w1T[64 * 264];  // bf16 w1^T [n][k], pitch 264
  __shared__ int sb[2];
  __shared__ float sm[4], sd[4];

  const int tid = threadIdx.x;
  const int w = tid >> 6, lane = tid & 63, q = lane >> 4, c = lane & 15;
  const int seg = blockIdx.x >> 1, p = blockIdx.x & 1;

  if (tid < 2) {  // lower_bound(batch, seg) / lower_bound(batch, seg+1)
    int target = seg + tid;
    int lo = 0, hi = N_NODES;
    while (lo < hi) { int mid = (lo + hi) >> 1; if (batch[mid] < target) lo = mid + 1; else hi = mid; }
    sb[tid] = lo;
  }
  for (int i = tid; i < 256 * 64; i += 256) {  // i = k*64 + n, coalesced
    int k = i >> 6, n = i & 63;
    w1T[n * 264 + k] = (short)f2bf_rne(w1[i]);
  }
  __syncthreads();

  const int s0 = sb[0], e0 = sb[1];
  const int len = e0 - s0;
  const int ps = s0 + ((len * p) >> 1);
  const int pe = s0 + ((len * (p + 1)) >> 1);
  const int plen = pe - ps;

  float b1v[4], w2v[4];
#pragma unroll
  for (int nt = 0; nt < 4; ++nt) { b1v[nt] = b1[nt * 16 + c]; w2v[nt] = w2[nt * 16 + c]; }
  const float b2v = b2[0];

  f32x4 sum = (f32x4){0.f, 0.f, 0.f, 0.f};
  f32x4 mx  = (f32x4){-INFINITY, -INFINITY, -INFINITY, -INFINITY};
  f32x4 at  = (f32x4){0.f, 0.f, 0.f, 0.f};
  float den = 0.f, m = -INFINITY;

  const int ntiles = (plen + 15) >> 4;
  for (int t = w; t < ntiles; t += 4) {
    const int r0 = ps + (t << 4);
    const int lim = min(16, pe - r0);   // wave-uniform

    // A-fragment loads: row = r0 + c (clamped), k = kt*32 + q*8 + j
    const int rowA = r0 + (c < lim ? c : 0);
    const float* ap = x + (size_t)rowA * HID + q * 8;
    float4 fa0[8], fa1[8];
#pragma unroll
    for (int kt = 0; kt < 8; ++kt) {
      fa0[kt] = *(const float4*)(ap + kt * 32);
      fa1[kt] = *(const float4*)(ap + kt * 32 + 4);
    }
    union { s16x8 v; unsigned int u[4]; } ah[8];
#pragma unroll
    for (int kt = 0; kt < 8; ++kt) {
      ah[kt].u[0] = pack2_bf16_rne(fa0[kt].x, fa0[kt].y);
      ah[kt].u[1] = pack2_bf16_rne(fa0[kt].z, fa0[kt].w);
      ah[kt].u[2] = pack2_bf16_rne(fa1[kt].x, fa1[kt].y);
      ah[kt].u[3] = pack2_bf16_rne(fa1[kt].z, fa1[kt].w);
    }

    f32x4 acc[4];
#pragma unroll
    for (int nt = 0; nt < 4; ++nt) acc[nt] = (f32x4){0.f, 0.f, 0.f, 0.f};
#pragma unroll
    for (int kt = 0; kt < 8; ++kt) {
#pragma unroll
      for (int nt = 0; nt < 4; ++nt) {
        s16x8 bh = *(const s16x8*)&w1T[(nt * 16 + c) * 264 + kt * 32 + q * 8];
        acc[nt] = __builtin_amdgcn_mfma_f32_16x16x32_bf16(ah[kt].v, bh, acc[nt], 0, 0, 0);
      }
    }

    // epilogue: D[row=4q+r][col=nt*16+c]; butterfly over c -> gr[r] = g(row 4q+r)
    float gr[4];
#pragma unroll
    for (int r = 0; r < 4; ++r) {
      float sv = 0.f;
#pragma unroll
      for (int nt = 0; nt < 4; ++nt) {
        float h = acc[nt][r] + b1v[nt];
        h = h > 0.f ? h : 0.f;
        sv += h * w2v[nt];
      }
      sv += __shfl_xor(sv, 1, 64);
      sv += __shfl_xor(sv, 2, 64);
      sv += __shfl_xor(sv, 4, 64);
      sv += __shfl_xor(sv, 8, 64);
      gr[r] = sv + b2v;
    }

    // gather all 16 row-gates; tile max over valid rows
    float gv16[16];
    float gm = -INFINITY;
#pragma unroll
    for (int i = 0; i < 16; ++i) {
      gv16[i] = __shfl(gr[i & 3], (i >> 2) << 4, 64);
      if (i < lim) gm = fmaxf(gm, gv16[i]);
    }
    float m_new = fmaxf(m, gm);
    float alpha = (m == -INFINITY) ? 0.f : __expf(m - m_new);
    at = at * alpha;
    den *= alpha;
    m = m_new;

    // pool update: per-row load (cache-hot line, just touched by A-loads)
#pragma unroll
    for (int i = 0; i < 16; ++i) {
      if (i < lim) {   // wave-uniform
        float4 v = *(const float4*)(x + (size_t)(r0 + i) * HID + lane * 4);
        float ei = __expf(gv16[i] - m_new);
        den += ei;
        f32x4 f = (f32x4){v.x, v.y, v.z, v.w};
        sum = sum + f;
        mx[0] = fmaxf(mx[0], f[0]); mx[1] = fmaxf(mx[1], f[1]);
        mx[2] = fmaxf(mx[2], f[2]); mx[3] = fmaxf(mx[3], f[3]);
        at[0] = fmaf(ei, f[0], at[0]); at[1] = fmaf(ei, f[1], at[1]);
        at[2] = fmaf(ei, f[2], at[2]); at[3] = fmaf(ei, f[3], at[3]);
      }
    }
  }

  __syncthreads();                 // done with w1T; reuse as merge scratch
  float* scr = (float*)w1T;        // 3072 floats = 12 KB
  {
    float* p0 = scr + (w * 3 + 0) * 256;
    float* p1 = scr + (w * 3 + 1) * 256;
    float* p2 = scr + (w * 3 + 2) * 256;
    int f = lane * 4;
#pragma unroll
    for (int j = 0; j < 4; ++j) { p0[f + j] = sum[j]; p1[f + j] = mx[j]; p2[f + j] = at[j]; }
    if (lane == 0) { sm[w] = m; sd[w] = den; }
  }
  __syncthreads();
  {
    int f = tid;
    float M = fmaxf(fmaxf(sm[0], sm[1]), fmaxf(sm[2], sm[3]));
    float S = 0.f, MX = -INFINITY, A = 0.f, D = 0.f;
#pragma unroll
    for (int ww = 0; ww < 4; ++ww) {
      float sc = (sm[ww] == -INFINITY) ? 0.f : __expf(sm[ww] - M);
      S += scr[(ww * 3 + 0) * 256 + f];
      MX = fmaxf(MX, scr[(ww * 3 + 1) * 256 + f]);
      A = fmaf(sc, scr[(ww * 3 + 2) * 256 + f], A);
      D = fmaf(sc, sd[ww], D);
    }
    float* pr = pbuf + (size_t)blockIdx.x * 772;
    pr[f] = S; pr[256 + f] = MX; pr[512 + f] = A;
    if (tid == 0) { pr[768] = M; pr[769] = D; pr[770] = (float)plen; }
  }
}

// ---------------------------------------------------------------------------
// Kernel 2: merge the 2 partials per segment -> z (512 x 768 fp32).
// ---------------------------------------------------------------------------
__global__ __launch_bounds__(256) void pool_merge(
    const float* __restrict__ pbuf, float* __restrict__ zbuf)
{
  const int seg = blockIdx.x;
  const int f = threadIdx.x;
  const float* pa = pbuf + (size_t)(seg * 2) * 772;
  const float* pb = pa + 772;
  float m0 = pa[768], d0 = pa[769], c0 = pa[770];
  float m1 = pb[768], d1 = pb[769], c1 = pb[770];
  float M = fmaxf(m0, m1);
  float sc0 = (m0 == -INFINITY) ? 0.f : __expf(m0 - M);
  float sc1 = (m1 == -INFINITY) ? 0.f : __expf(m1 - M);
  float D = sc0 * d0 + sc1 * d1;
  float cnt = c0 + c1;
  float S  = pa[f] + pb[f];
  float MX = fmaxf(pa[256 + f], pb[256 + f]);
  float A  = sc0 * pa[512 + f] + sc1 * pb[512 + f];
  float* zr = zbuf + (size_t)seg * 768;
  zr[f]       = (cnt > 0.f) ? S / cnt : 0.f;
  zr[256 + f] = (cnt > 0.f) ? MX : 0.f;
  zr[512 + f] = (cnt > 0.f) ? A / fmaxf(D, 1e-16f) : 0.f;
}

// ---------------------------------------------------------------------------
// Kernel 3: y = z @ wp + bp, LayerNorm, fp32 out. Block = 1 graph; k-dim
// split across 4 waves; wp loaded as float4.
// ---------------------------------------------------------------------------
__global__ __launch_bounds__(256) void head_ln(
    const float* __restrict__ zbuf, const float* __restrict__ wp,
    const float* __restrict__ bp, const float* __restrict__ gam,
    const float* __restrict__ bet, float* __restrict__ out)
{
  const int g = blockIdx.x;
  const int tid = threadIdx.x;
  const int w = tid >> 6, lane = tid & 63;
  __shared__ float z[768];
  __shared__ __align__(16) float part[4][256];
  __shared__ float red[256];

  for (int i = tid; i < 768; i += 256) z[i] = zbuf[(size_t)g * 768 + i];
  __syncthreads();

  f32x4 acc = (f32x4){0.f, 0.f, 0.f, 0.f};
  const float4* wp4 = (const float4*)wp;  // wp[k*256 + lane*4] = wp4[k*64 + lane]
  const int k0 = w * 192;
#pragma unroll 8
  for (int k = k0; k < k0 + 192; ++k) {
    float4 wv = wp4[(size_t)k * 64 + lane];
    float zk = z[k];
    acc[0] = fmaf(zk, wv.x, acc[0]);
    acc[1] = fmaf(zk, wv.y, acc[1]);
    acc[2] = fmaf(zk, wv.z, acc[2]);
    acc[3] = fmaf(zk, wv.w, acc[3]);
  }
  *(f32x4*)&part[w][lane * 4] = acc;
  __syncthreads();

  const int t = tid;
  float y = bp[t] + part[0][t] + part[1][t] + part[2][t] + part[3][t];

  red[t] = y;
  __syncthreads();
  for (int wd = 128; wd > 0; wd >>= 1) {
    if (t < wd) red[t] += red[t + wd];
    __syncthreads();
  }
  const float mu = red[0] * (1.f / 256.f);
  __syncthreads();
  float d = y - mu;
  red[t] = d * d;
  __syncthreads();
  for (int wd = 128; wd > 0; wd >>= 1) {
    if (t < wd) red[t] += red[t + wd];
    __syncthreads();
  }
  const float var = red[0] * (1.f / 256.f);
  const float is = rsqrtf(var + 1e-5f);
  out[(size_t)g * 256 + t] = fmaf(d * is, gam[t], bet[t]);
}

// ---------------------------------------------------------------------------
extern "C" void kernel_launch(void* const* d_in, const int* in_sizes, int n_in,
                              void* d_out, int out_size, void* d_ws, size_t ws_size,
                              hipStream_t stream) {
  const float* x   = (const float*)d_in[0];
  const int*   bat = (const int*)d_in[1];
  const float* w1  = (const float*)d_in[2];
  const float* b1  = (const float*)d_in[3];
  const float* w2  = (const float*)d_in[4];
  const float* b2  = (const float*)d_in[5];
  const float* wp  = (const float*)d_in[6];
  const float* bp  = (const float*)d_in[7];
  const float* gam = (const float*)d_in[8];
  const float* bet = (const float*)d_in[9];
  float* out = (float*)d_out;

  // ws layout: pbuf 1024*772 f32 @ 0; zbuf 512*768 f32 after.
  float* pbuf = (float*)d_ws;
  float* zbuf = (float*)((char*)d_ws + (size_t)1024 * 772 * 4);

  hipLaunchKernelGGL(pool_partial, dim3(NGRAPH * 2), dim3(256), 0, stream,
                     x, bat, w1, b1, w2, b2, pbuf);
  hipLaunchKernelGGL(pool_merge, dim3(NGRAPH), dim3(256), 0, stream, pbuf, zbuf);
  hipLaunchKernelGGL(head_ln, dim3(NGRAPH), dim3(256), 0, stream,
                     zbuf, wp, bp, gam, bet, out);
}

// Round 7
// 357.864 us; speedup vs baseline: 1.2214x; 1.1134x over previous
//
#include <hip/hip_runtime.h>
#include <math.h>

#define N_NODES 200000
#define NGRAPH  512
#define HID     256

typedef __attribute__((ext_vector_type(8))) short s16x8;
typedef __attribute__((ext_vector_type(4))) float f32x4;

__device__ __forceinline__ unsigned short f2bf_rne(float f) {
  unsigned int u = __float_as_uint(f);
  return (unsigned short)((u + 0x7fffu + ((u >> 16) & 1u)) >> 16);
}
__device__ __forceinline__ unsigned int pack2_bf16_rne(float a, float b) {
  unsigned int ua = __float_as_uint(a), ub = __float_as_uint(b);
  unsigned int ra = (ua + 0x7fffu + ((ua >> 16) & 1u)) >> 16;
  unsigned int rb = (ub + 0x7fffu + ((ub >> 16) & 1u)) & 0xffff0000u;
  return ra | rb;
}

// ---------------------------------------------------------------------------
// Kernel 1: per-part fused gate+pool partials. Block = (segment, half).
// Barrier-free hot loop. Register-pressure-shaped to avoid scratch spills
// (R5/R6 lesson: fa[16]+gv16[16] arrays -> 84-92 MB spill traffic):
//   - A-fragments converted in two 4-kt halves (<=32 load VGPRs in flight)
//   - no gate-value array: pool loop shuffles from gr[4]; tile max in-register
//   - __launch_bounds__(256,2): cap 256 VGPRs, allocator must not spill-to-fit
// ---------------------------------------------------------------------------
__global__ __launch_bounds__(256, 2) void pool_partial(
    const float* __restrict__ x, const int* __restrict__ batch,
    const float* __restrict__ w1, const float* __restrict__ b1,
    const float* __restrict__ w2, const float* __restrict__ b2,
    float* __restrict__ pbuf)
{
  __shared__ __align__(16) short w1T[64 * 264];  // bf16 w1^T [n][k], pitch 264
  __shared__ int sb[2];
  __shared__ float sm[4], sd[4];

  const int tid = threadIdx.x;
  const int w = tid >> 6, lane = tid & 63, q = lane >> 4, c = lane & 15;
  const int seg = blockIdx.x >> 1, p = blockIdx.x & 1;

  if (tid < 2) {  // lower_bound(batch, seg) / lower_bound(batch, seg+1)
    int target = seg + tid;
    int lo = 0, hi = N_NODES;
    while (lo < hi) { int mid = (lo + hi) >> 1; if (batch[mid] < target) lo = mid + 1; else hi = mid; }
    sb[tid] = lo;
  }
  for (int i = tid; i < 256 * 64; i += 256) {  // i = k*64 + n, coalesced
    int k = i >> 6, n = i & 63;
    w1T[n * 264 + k] = (short)f2bf_rne(w1[i]);
  }
  __syncthreads();

  const int s0 = sb[0], e0 = sb[1];
  const int len = e0 - s0;
  const int ps = s0 + ((len * p) >> 1);
  const int pe = s0 + ((len * (p + 1)) >> 1);
  const int plen = pe - ps;

  float b1v[4], w2v[4];
#pragma unroll
  for (int nt = 0; nt < 4; ++nt) { b1v[nt] = b1[nt * 16 + c]; w2v[nt] = w2[nt * 16 + c]; }
  const float b2v = b2[0];

  f32x4 sum = (f32x4){0.f, 0.f, 0.f, 0.f};
  f32x4 mx  = (f32x4){-INFINITY, -INFINITY, -INFINITY, -INFINITY};
  f32x4 at  = (f32x4){0.f, 0.f, 0.f, 0.f};
  float den = 0.f, m = -INFINITY;

  const int ntiles = (plen + 15) >> 4;
  for (int t = w; t < ntiles; t += 4) {
    const int r0 = ps + (t << 4);
    const int lim = min(16, pe - r0);   // wave-uniform

    // A-fragments: row = r0 + c (clamped), k = kt*32 + q*8 + j.
    // Two halves of 4 kt each: at most 8 float4 (32 VGPRs) in flight.
    const int rowA = r0 + (c < lim ? c : 0);
    const float* ap = x + (size_t)rowA * HID + q * 8;
    union { s16x8 v; unsigned int u[4]; } ah[8];
#pragma unroll
    for (int half = 0; half < 2; ++half) {
      float4 t0[4], t1[4];
#pragma unroll
      for (int kk = 0; kk < 4; ++kk) {
        int kt = half * 4 + kk;
        t0[kk] = *(const float4*)(ap + kt * 32);
        t1[kk] = *(const float4*)(ap + kt * 32 + 4);
      }
#pragma unroll
      for (int kk = 0; kk < 4; ++kk) {
        int kt = half * 4 + kk;
        ah[kt].u[0] = pack2_bf16_rne(t0[kk].x, t0[kk].y);
        ah[kt].u[1] = pack2_bf16_rne(t0[kk].z, t0[kk].w);
        ah[kt].u[2] = pack2_bf16_rne(t1[kk].x, t1[kk].y);
        ah[kt].u[3] = pack2_bf16_rne(t1[kk].z, t1[kk].w);
      }
    }

    f32x4 acc[4];
#pragma unroll
    for (int nt = 0; nt < 4; ++nt) acc[nt] = (f32x4){0.f, 0.f, 0.f, 0.f};
#pragma unroll
    for (int kt = 0; kt < 8; ++kt) {
#pragma unroll
      for (int nt = 0; nt < 4; ++nt) {
        s16x8 bh = *(const s16x8*)&w1T[(nt * 16 + c) * 264 + kt * 32 + q * 8];
        acc[nt] = __builtin_amdgcn_mfma_f32_16x16x32_bf16(ah[kt].v, bh, acc[nt], 0, 0, 0);
      }
    }

    // epilogue: D[row=4q+r][col=nt*16+c]; butterfly over c -> gr[r] uniform
    // across the 16 lanes of quad q; gr[r] = gate(row 4q+r).
    float gr[4];
#pragma unroll
    for (int r = 0; r < 4; ++r) {
      float sv = 0.f;
#pragma unroll
      for (int nt = 0; nt < 4; ++nt) {
        float h = acc[nt][r] + b1v[nt];
        h = h > 0.f ? h : 0.f;
        sv += h * w2v[nt];
      }
      sv += __shfl_xor(sv, 1, 64);
      sv += __shfl_xor(sv, 2, 64);
      sv += __shfl_xor(sv, 4, 64);
      sv += __shfl_xor(sv, 8, 64);
      gr[r] = sv + b2v;
    }

    // tile max in-register: mask invalid rows, reduce over r then quads
    float gm = -INFINITY;
#pragma unroll
    for (int r = 0; r < 4; ++r)
      gm = fmaxf(gm, (4 * q + r < lim) ? gr[r] : -INFINITY);
    gm = fmaxf(gm, __shfl_xor(gm, 16, 64));
    gm = fmaxf(gm, __shfl_xor(gm, 32, 64));

    float m_new = fmaxf(m, gm);
    float alpha = (m == -INFINITY) ? 0.f : __expf(m - m_new);
    at = at * alpha;
    den *= alpha;
    m = m_new;

    // pool update: per-row load (L1/L2-hot: same lines as the A-loads)
#pragma unroll
    for (int i = 0; i < 16; ++i) {
      if (i < lim) {   // wave-uniform
        float gv = __shfl(gr[i & 3], (i >> 2) << 4, 64);
        float4 v = *(const float4*)(x + (size_t)(r0 + i) * HID + lane * 4);
        float ei = __expf(gv - m_new);
        den += ei;
        f32x4 f = (f32x4){v.x, v.y, v.z, v.w};
        sum = sum + f;
        mx[0] = fmaxf(mx[0], f[0]); mx[1] = fmaxf(mx[1], f[1]);
        mx[2] = fmaxf(mx[2], f[2]); mx[3] = fmaxf(mx[3], f[3]);
        at[0] = fmaf(ei, f[0], at[0]); at[1] = fmaf(ei, f[1], at[1]);
        at[2] = fmaf(ei, f[2], at[2]); at[3] = fmaf(ei, f[3], at[3]);
      }
    }
  }

  __syncthreads();                 // done with w1T; reuse as merge scratch
  float* scr = (float*)w1T;        // 3072 floats = 12 KB
  {
    float* p0 = scr + (w * 3 + 0) * 256;
    float* p1 = scr + (w * 3 + 1) * 256;
    float* p2 = scr + (w * 3 + 2) * 256;
    int f = lane * 4;
#pragma unroll
    for (int j = 0; j < 4; ++j) { p0[f + j] = sum[j]; p1[f + j] = mx[j]; p2[f + j] = at[j]; }
    if (lane == 0) { sm[w] = m; sd[w] = den; }
  }
  __syncthreads();
  {
    int f = tid;
    float M = fmaxf(fmaxf(sm[0], sm[1]), fmaxf(sm[2], sm[3]));
    float S = 0.f, MX = -INFINITY, A = 0.f, D = 0.f;
#pragma unroll
    for (int ww = 0; ww < 4; ++ww) {
      float sc = (sm[ww] == -INFINITY) ? 0.f : __expf(sm[ww] - M);
      S += scr[(ww * 3 + 0) * 256 + f];
      MX = fmaxf(MX, scr[(ww * 3 + 1) * 256 + f]);
      A = fmaf(sc, scr[(ww * 3 + 2) * 256 + f], A);
      D = fmaf(sc, sd[ww], D);
    }
    float* pr = pbuf + (size_t)blockIdx.x * 772;
    pr[f] = S; pr[256 + f] = MX; pr[512 + f] = A;
    if (tid == 0) { pr[768] = M; pr[769] = D; pr[770] = (float)plen; }
  }
}

// ---------------------------------------------------------------------------
// Kernel 2: merge the 2 partials per segment -> z (512 x 768 fp32).
// ---------------------------------------------------------------------------
__global__ __launch_bounds__(256) void pool_merge(
    const float* __restrict__ pbuf, float* __restrict__ zbuf)
{
  const int seg = blockIdx.x;
  const int f = threadIdx.x;
  const float* pa = pbuf + (size_t)(seg * 2) * 772;
  const float* pb = pa + 772;
  float m0 = pa[768], d0 = pa[769], c0 = pa[770];
  float m1 = pb[768], d1 = pb[769], c1 = pb[770];
  float M = fmaxf(m0, m1);
  float sc0 = (m0 == -INFINITY) ? 0.f : __expf(m0 - M);
  float sc1 = (m1 == -INFINITY) ? 0.f : __expf(m1 - M);
  float D = sc0 * d0 + sc1 * d1;
  float cnt = c0 + c1;
  float S  = pa[f] + pb[f];
  float MX = fmaxf(pa[256 + f], pb[256 + f]);
  float A  = sc0 * pa[512 + f] + sc1 * pb[512 + f];
  float* zr = zbuf + (size_t)seg * 768;
  zr[f]       = (cnt > 0.f) ? S / cnt : 0.f;
  zr[256 + f] = (cnt > 0.f) ? MX : 0.f;
  zr[512 + f] = (cnt > 0.f) ? A / fmaxf(D, 1e-16f) : 0.f;
}

// ---------------------------------------------------------------------------
// Kernel 3: y = z @ wp + bp, LayerNorm, fp32 out. Block = 1 graph; k-dim
// split across 4 waves; wp loaded as float4.
// ---------------------------------------------------------------------------
__global__ __launch_bounds__(256) void head_ln(
    const float* __restrict__ zbuf, const float* __restrict__ wp,
    const float* __restrict__ bp, const float* __restrict__ gam,
    const float* __restrict__ bet, float* __restrict__ out)
{
  const int g = blockIdx.x;
  const int tid = threadIdx.x;
  const int w = tid >> 6, lane = tid & 63;
  __shared__ float z[768];
  __shared__ __align__(16) float part[4][256];
  __shared__ float red[256];

  for (int i = tid; i < 768; i += 256) z[i] = zbuf[(size_t)g * 768 + i];
  __syncthreads();

  f32x4 acc = (f32x4){0.f, 0.f, 0.f, 0.f};
  const float4* wp4 = (const float4*)wp;  // wp[k*256 + lane*4] = wp4[k*64 + lane]
  const int k0 = w * 192;
#pragma unroll 8
  for (int k = k0; k < k0 + 192; ++k) {
    float4 wv = wp4[(size_t)k * 64 + lane];
    float zk = z[k];
    acc[0] = fmaf(zk, wv.x, acc[0]);
    acc[1] = fmaf(zk, wv.y, acc[1]);
    acc[2] = fmaf(zk, wv.z, acc[2]);
    acc[3] = fmaf(zk, wv.w, acc[3]);
  }
  *(f32x4*)&part[w][lane * 4] = acc;
  __syncthreads();

  const int t = tid;
  float y = bp[t] + part[0][t] + part[1][t] + part[2][t] + part[3][t];

  red[t] = y;
  __syncthreads();
  for (int wd = 128; wd > 0; wd >>= 1) {
    if (t < wd) red[t] += red[t + wd];
    __syncthreads();
  }
  const float mu = red[0] * (1.f / 256.f);
  __syncthreads();
  float d = y - mu;
  red[t] = d * d;
  __syncthreads();
  for (int wd = 128; wd > 0; wd >>= 1) {
    if (t < wd) red[t] += red[t + wd];
    __syncthreads();
  }
  const float var = red[0] * (1.f / 256.f);
  const float is = rsqrtf(var + 1e-5f);
  out[(size_t)g * 256 + t] = fmaf(d * is, gam[t], bet[t]);
}

// ---------------------------------------------------------------------------
extern "C" void kernel_launch(void* const* d_in, const int* in_sizes, int n_in,
                              void* d_out, int out_size, void* d_ws, size_t ws_size,
                              hipStream_t stream) {
  const float* x   = (const float*)d_in[0];
  const int*   bat = (const int*)d_in[1];
  const float* w1  = (const float*)d_in[2];
  const float* b1  = (const float*)d_in[3];
  const float* w2  = (const float*)d_in[4];
  const float* b2  = (const float*)d_in[5];
  const float* wp  = (const float*)d_in[6];
  const float* bp  = (const float*)d_in[7];
  const float* gam = (const float*)d_in[8];
  const float* bet = (const float*)d_in[9];
  float* out = (float*)d_out;

  // ws layout: pbuf 1024*772 f32 @ 0; zbuf 512*768 f32 after.
  float* pbuf = (float*)d_ws;
  float* zbuf = (float*)((char*)d_ws + (size_t)1024 * 772 * 4);

  hipLaunchKernelGGL(pool_partial, dim3(NGRAPH * 2), dim3(256), 0, stream,
                     x, bat, w1, b1, w2, b2, pbuf);
  hipLaunchKernelGGL(pool_merge, dim3(NGRAPH), dim3(256), 0, stream, pbuf, zbuf);
  hipLaunchKernelGGL(head_ln, dim3(NGRAPH), dim3(256), 0, stream,
                     zbuf, wp, bp, gam, bet, out);
}